// Round 14
// baseline (283.357 us; speedup 1.0000x reference)
//
#include <hip/hip_runtime.h>
#include <stdint.h>

// ReconstructionDecoder — r14 DIAGNOSTIC (retry of r13 with better design).
// r13's container failure audits as infra (all indices in-bounds, uniform
// barriers); retrying. Design change: amplify ONLY prep(x8) and decode2(x8),
// gemm3 x1. Two measurement channels:
//   dur_us = base + 7*(p+d)            -> recovers p+d
//   top-5  = 8*max(p,d) instances      -> recovers max(p,d)
// together -> p and d individually; gemm3+gaps = 63 - p - d.
// Kernels are idempotent -> passed/absmax unchanged.

#define D_ 256
#define E_ 512

typedef __attribute__((ext_vector_type(8))) short short8;
typedef __attribute__((ext_vector_type(4))) short short4v;
typedef __attribute__((ext_vector_type(4))) float f32x4;
typedef __attribute__((ext_vector_type(2))) float f32x2;

// ---- module-scope scratch (rewritten fully every launch; d_ws untouched) ----
__device__ alignas(16) unsigned short g_Abuf[2176 * 768];  // 3.34 MB
__device__ alignas(16) unsigned short g_Bbuf[768 * 640];   // 0.98 MB
__device__ alignas(16) float g_U[2048 * 512];              // 4 MB
__device__ alignas(16) float g_C[2048 * 128];              // 1 MB
__device__ alignas(16) float g_Vt[512 * 128];              // 256 KB
__device__ alignas(16) float g_GKW[512 * 4];
__device__ alignas(16) float g_sxt[2048];
__device__ alignas(16) float g_sqxt[2048];
__device__ alignas(16) float g_sf[128];
__device__ alignas(16) float g_sqf[128];

__device__ inline unsigned short f2bf(float f) {
  unsigned int u = __float_as_uint(f);
  u += 0x7fffu + ((u >> 16) & 1u);
  return (unsigned short)(u >> 16);
}
__device__ inline float bf2f(unsigned short h) {
  return __uint_as_float(((unsigned int)h) << 16);
}

// ---------------------------------------------------------------------------
// prep (grid 600) — r12 body, rep-looped (reps=8 diagnostic).
// ---------------------------------------------------------------------------
__global__ __launch_bounds__(256) void prep(
    const float* __restrict__ x, const float* __restrict__ t_emb,
    const float* __restrict__ f_emb, const float* __restrict__ ln_g,
    const float* __restrict__ ln_b, const float* __restrict__ W1,
    const float* __restrict__ b1, const float* __restrict__ W2, int reps) {
  __shared__ float sW[32][264];
  __shared__ float sF[128][36];
  __shared__ float sg[32];
  __shared__ float red[4][64][2];

  const int blk = blockIdx.x;
  const int tid = threadIdx.x;
  const int wv = tid >> 6;
  const int l = tid & 63;

  for (int rep = 0; rep < reps; ++rep) {
    if (blk < 544) {
      int arow;
      float v0, v1, v2, v3;
      if (blk < 512) {
        const int r = blk * 4 + wv;  // 0..2047
        const int bn = r >> 7, t = r & 127;
        const float4 xv = *(const float4*)(x + bn * D_ + 4 * l);
        const float4 tv = *(const float4*)(t_emb + t * D_ + 4 * l);
        v0 = xv.x + tv.x; v1 = xv.y + tv.y;
        v2 = xv.z + tv.z; v3 = xv.w + tv.w;
        arow = r;
      } else {
        const int fi = (blk - 512) * 4 + wv;  // 0..127
        const float4 fv = *(const float4*)(f_emb + fi * D_ + 4 * l);
        v0 = fv.x; v1 = fv.y; v2 = fv.z; v3 = fv.w;
        arow = 2048 + fi;
      }
      union { unsigned short u[4]; short4v v; } hi, lo;
      hi.u[0] = f2bf(v0); hi.u[1] = f2bf(v1);
      hi.u[2] = f2bf(v2); hi.u[3] = f2bf(v3);
      lo.u[0] = f2bf(v0 - bf2f(hi.u[0]));
      lo.u[1] = f2bf(v1 - bf2f(hi.u[1]));
      lo.u[2] = f2bf(v2 - bf2f(hi.u[2]));
      lo.u[3] = f2bf(v3 - bf2f(hi.u[3]));
      unsigned short* ab = g_Abuf + arow * 768 + 4 * l;
      *(short4v*)(ab) = hi.v;
      *(short4v*)(ab + 256) = lo.v;
      *(short4v*)(ab + 512) = hi.v;
      float s = (v0 + v1) + (v2 + v3);
      float q = fmaf(v0, v0, fmaf(v1, v1, fmaf(v2, v2, v3 * v3)));
#pragma unroll
      for (int d = 1; d < 64; d <<= 1) {
        s += __shfl_xor(s, d);
        q += __shfl_xor(q, d);
      }
      if (l == 0) {
        if (arow < 2048) { g_sxt[arow] = s; g_sqxt[arow] = q; }
        else             { g_sf[arow - 2048] = s; g_sqf[arow - 2048] = q; }
      }
    } else if (blk < 552) {
      const int e = (blk - 544) * 64 + l;
      const int k0 = wv * 64;
      float G = 0.f, K = 0.f;
#pragma unroll 8
      for (int i = 0; i < 64; ++i) {
        const float wval = W1[(k0 + i) * E_ + e];
        G = fmaf(ln_g[k0 + i], wval, G);
        K = fmaf(ln_b[k0 + i], wval, K);
      }
      red[wv][l][0] = G;
      red[wv][l][1] = K;
      __syncthreads();
      if (wv == 0) {
        G = (red[0][l][0] + red[1][l][0]) + (red[2][l][0] + red[3][l][0]);
        K = (red[0][l][1] + red[1][l][1]) + (red[2][l][1] + red[3][l][1]);
        float4 o;
        o.x = G; o.y = K + b1[e];
        o.z = W2[2 * e]; o.w = W2[2 * e + 1];
        *(float4*)(g_GKW + 4 * e) = o;
      }
    } else {
      const int b = blk - 552;         // 0..47
      const int kt = b >> 1, h = b & 1;
      const int term = kt >> 3;        // 0,1: hi; 2: lo
      const int k0 = (kt & 7) * 32;
      {
        const float4* w4 = (const float4*)(W1 + (size_t)k0 * E_ + h * 256);
        for (int i = tid; i < 2048; i += 256) {
          const int kk2 = i >> 6, c4 = i & 63;
          *(float4*)&sW[kk2][c4 * 4] = w4[kk2 * (E_ / 4) + c4];
        }
        if (tid < 32) sg[tid] = ln_g[k0 + tid];
        if (h == 0) {
          const float4* f4 = (const float4*)(f_emb + k0);
          for (int i = tid; i < 1024; i += 256) {
            const int fr = i >> 3, c4 = i & 7;
            *(float4*)&sF[fr][c4 * 4] = f4[fr * (D_ / 4) + c4];
          }
        }
      }
      __syncthreads();
      for (int fi = tid; fi < 1024; fi += 256) {
        const int ct = 4 * h + (fi >> 8);
        const int rem = fi & 255;
        const int jtl = rem >> 6, ln = rem & 63;
        const int colw = (ct - 4 * h) * 64 + jtl * 16 + (ln & 15);
        const int kb = ((ln >> 4) & 3) * 8;
        union { unsigned short u[8]; short8 v; } fr8;
#pragma unroll
        for (int j = 0; j < 8; ++j) {
          const float v = sg[kb + j] * sW[kb + j][colw];
          const unsigned short hv = f2bf(v);
          fr8.u[j] = (term == 2) ? f2bf(v - bf2f(hv)) : hv;
        }
        const int gidx = ((kt * 10 + ct) * 4 + jtl) * 64 + ln;
        *(short8*)(g_Bbuf + gidx * 8) = fr8.v;
      }
      if (h == 0) {
        for (int fi = tid; fi < 512; fi += 256) {
          const int ct = 8 + (fi >> 8);
          const int rem = fi & 255;
          const int jtl = rem >> 6, ln = rem & 63;
          const int f = (ct - 8) * 64 + jtl * 16 + (ln & 15);
          const int kb = ((ln >> 4) & 3) * 8;
          union { unsigned short u[8]; short8 v; } fr8;
#pragma unroll
          for (int j = 0; j < 8; ++j) {
            const float v = sF[f][kb + j];
            const unsigned short hv = f2bf(v);
            fr8.u[j] = (term == 2) ? f2bf(v - bf2f(hv)) : hv;
          }
          const int gidx = ((kt * 10 + ct) * 4 + jtl) * 64 + ln;
          *(short8*)(g_Bbuf + gidx * 8) = fr8.v;
        }
      }
    }
    __syncthreads();                   // LDS reuse safe across reps
    asm volatile("" ::: "memory");     // defeat cross-rep LICM/CSE
  }
}

// ---------------------------------------------------------------------------
// gemm3 (grid 170) — r12 body; loop present but reps=1 (NOT amplified).
// ---------------------------------------------------------------------------
__global__ __launch_bounds__(256) void gemm3(int reps) {
  const int tid = threadIdx.x;
  const int wave = tid >> 6, lane = tid & 63;
  const int quad = (lane >> 4) & 3, n16 = lane & 15;
  const int rt = blockIdx.x / 10, ct = blockIdx.x % 10;
  const int rowb = rt * 128 + wave * 32;

  const unsigned short* a0 = g_Abuf + (size_t)(rowb + n16) * 768 + quad * 8;
  const unsigned short* a1 = a0 + 16 * 768;

  for (int rep = 0; rep < reps; ++rep) {
    f32x4 acc[2][4];
#pragma unroll
    for (int j = 0; j < 4; ++j) {
      acc[0][j] = (f32x4){0.f, 0.f, 0.f, 0.f};
      acc[1][j] = (f32x4){0.f, 0.f, 0.f, 0.f};
    }

#pragma unroll 4
    for (int kt = 0; kt < 24; ++kt) {
      const short8 av0 = *(const short8*)(a0 + kt * 32);
      const short8 av1 = *(const short8*)(a1 + kt * 32);
      const short8* bp =
          (const short8*)g_Bbuf + ((kt * 10 + ct) * 4) * 64 + lane;
#pragma unroll
      for (int jtl = 0; jtl < 4; ++jtl) {
        const short8 bf = bp[jtl * 64];
        acc[0][jtl] = __builtin_amdgcn_mfma_f32_16x16x32_bf16(av0, bf,
                                                              acc[0][jtl], 0, 0, 0);
        acc[1][jtl] = __builtin_amdgcn_mfma_f32_16x16x32_bf16(av1, bf,
                                                              acc[1][jtl], 0, 0, 0);
      }
    }

#pragma unroll
    for (int g = 0; g < 2; ++g)
#pragma unroll
      for (int jtl = 0; jtl < 4; ++jtl)
#pragma unroll
        for (int r = 0; r < 4; ++r) {
          const float val = acc[g][jtl][r];
          const int grow = rowb + g * 16 + quad * 4 + r;
          const int col = ct * 64 + jtl * 16 + n16;
          if (rt < 16) {
            if (ct < 8) g_U[grow * 512 + col] = val;
            else        g_C[grow * 128 + (col - 512)] = val;
          } else if (ct < 8) {
            g_Vt[col * 128 + (grow - 2048)] = val;
          }
        }
    asm volatile("" ::: "memory");
  }
}

// ---------------------------------------------------------------------------
// decode2 (grid 512 x 512thr) — r12 body, rep-looped (reps=8 diagnostic).
// ---------------------------------------------------------------------------
__global__ __launch_bounds__(512) void decode2(const float* __restrict__ b2,
                                               float* __restrict__ out,
                                               int reps) {
  __shared__ alignas(16) float sU[4][512];     // 8 KB
  __shared__ alignas(16) float sGKW[512 * 4];  // 8 KB
  __shared__ float part[8][64][17];            // 34.8 KB
  const int tid = threadIdx.x;
  const int w = tid >> 6, lane = tid & 63;
  const int bnt0 = blockIdx.x * 4;

  for (int rep = 0; rep < reps; ++rep) {
    ((float4*)sU)[tid] = ((const float4*)(g_U + (size_t)bnt0 * 512))[tid];
    ((float4*)sGKW)[tid] = ((const float4*)g_GKW)[tid];

    const f32x2 sf2 = *(const f32x2*)(g_sf + 2 * lane);
    const f32x2 sqf2 = *(const f32x2*)(g_sqf + 2 * lane);
    f32x2 Ar[4], Br[4];
#pragma unroll
    for (int ti = 0; ti < 4; ++ti) {
      const float sx = g_sxt[bnt0 + ti];
      const float sqx = g_sqxt[bnt0 + ti];
      const f32x2 c2 = *(const f32x2*)(g_C + (bnt0 + ti) * 128 + 2 * lane);
      const f32x2 mu = (sf2 + sx) * (1.0f / 256.0f);
      const f32x2 var = (sqf2 + 2.0f * c2 + sqx) * (1.0f / 256.0f) - mu * mu;
      f32x2 rs;
      rs.x = rsqrtf(var.x + 1e-5f);
      rs.y = rsqrtf(var.y + 1e-5f);
      Ar[ti] = rs;
      Br[ti] = -rs * mu;
    }
    __syncthreads();  // sU/sGKW staged

    f32x2 o0[4] = {(f32x2){0.f, 0.f}, (f32x2){0.f, 0.f},
                   (f32x2){0.f, 0.f}, (f32x2){0.f, 0.f}};
    f32x2 o1[4] = {(f32x2){0.f, 0.f}, (f32x2){0.f, 0.f},
                   (f32x2){0.f, 0.f}, (f32x2){0.f, 0.f}};
    const int ebase = __builtin_amdgcn_readfirstlane(w * 64);
#pragma unroll 8
    for (int ei = 0; ei < 64; ++ei) {
      const int e = ebase + ei;
      const float4 gkw = *(const float4*)(sGKW + 4 * e);
      const f32x2 v2 = *(const f32x2*)(g_Vt + e * 128 + 2 * lane);
#pragma unroll
      for (int ti = 0; ti < 4; ++ti) {
        const float u = sU[ti][e];
        const f32x2 s = v2 + u;
        const f32x2 pre = Ar[ti] * s + (Br[ti] * gkw.x + gkw.y);
        f32x2 y;
        y.x = fmaxf(pre.x, 0.f);
        y.y = fmaxf(pre.y, 0.f);
        o0[ti] += y * gkw.z;
        o1[ti] += y * gkw.w;
      }
    }
    __syncthreads();  // all sU reads done before part writes / next rep

#pragma unroll
    for (int ti = 0; ti < 4; ++ti) {
      part[w][lane][ti * 4 + 0] = o0[ti].x;
      part[w][lane][ti * 4 + 1] = o1[ti].x;
      part[w][lane][ti * 4 + 2] = o0[ti].y;
      part[w][lane][ti * 4 + 3] = o1[ti].y;
    }
    __syncthreads();

    const int t = tid >> 7, f = tid & 127;
    const int m = f >> 1, ff = f & 1;
    float r0 = b2[0], r1 = b2[1];
#pragma unroll
    for (int w2 = 0; w2 < 8; ++w2) {
      r0 += part[w2][m][t * 4 + ff * 2 + 0];
      r1 += part[w2][m][t * 4 + ff * 2 + 1];
    }
    float2 res;
    res.x = r0;
    res.y = r1;
    *(float2*)(out + ((bnt0 + t) * 128 + f) * 2) = res;
    __syncthreads();                 // part reuse safe across reps
    asm volatile("" ::: "memory");
  }
}

// ---------------------------------------------------------------------------
extern "C" void kernel_launch(void* const* d_in, const int* in_sizes, int n_in,
                              void* d_out, int out_size, void* d_ws,
                              size_t ws_size, hipStream_t stream) {
  const float* x = (const float*)d_in[0];
  const float* t_emb = (const float*)d_in[1];
  const float* f_emb = (const float*)d_in[2];
  const float* ln_g = (const float*)d_in[3];
  const float* ln_b = (const float*)d_in[4];
  const float* W1 = (const float*)d_in[5];
  const float* b1 = (const float*)d_in[6];
  const float* W2 = (const float*)d_in[7];
  const float* b2 = (const float*)d_in[8];
  (void)d_ws; (void)ws_size;

  prep<<<600, 256, 0, stream>>>(x, t_emb, f_emb, ln_g, ln_b, W1, b1, W2, 8);
  gemm3<<<170, 256, 0, stream>>>(1);
  decode2<<<512, 512, 0, stream>>>(b2, (float*)d_out, 8);
}